// Round 12
// baseline (275.948 us; speedup 1.0000x reference)
//
#include <hip/hip_runtime.h>
#include <cstddef>
#include <cstdint>

#define F 128
#define C_OUT 10
#define SB 256   // scan block size

typedef short bf16x8 __attribute__((ext_vector_type(8)));
typedef float f32x4  __attribute__((ext_vector_type(4)));
typedef float f32x2  __attribute__((ext_vector_type(2)));

// ---- bf16 pack helpers ----
__device__ __forceinline__ unsigned pack_bf16x2(float a, float b) {
  unsigned ua = __float_as_uint(a);
  unsigned ub = __float_as_uint(b);
  ua = (ua + 0x7FFFu + ((ua >> 16) & 1u)) >> 16;
  ub = (ub + 0x7FFFu + ((ub >> 16) & 1u)) >> 16;
  return ua | (ub << 16);
}
__device__ __forceinline__ unsigned short bf16_rne(float f) {
  unsigned u = __float_as_uint(f);
  return (unsigned short)((u + 0x7FFFu + ((u >> 16) & 1u)) >> 16);
}
// DIRTY unpack: {exact even col, odd col with <=2^-7 rel mantissa-extension noise}
// (drops the AND -> 2 VALU per uint instead of 3; noise is same order as the
// bf16 quantization already accepted, random-sign across edge sum)
__device__ __forceinline__ f32x2 unpk2(unsigned u) {
  f32x2 r;
  r.x = __uint_as_float(u << 16);
  r.y = __uint_as_float(u);
  return r;
}

// ---------------- GRU weight evolution (both layers) + zero counts ----------------
__global__ void gru_evolve2_k(const float* __restrict__ W01, const float* __restrict__ wih1,
                              const float* __restrict__ whh1, const float* __restrict__ bih1,
                              const float* __restrict__ bhh1,
                              const float* __restrict__ W02, const float* __restrict__ wih2,
                              const float* __restrict__ whh2, const float* __restrict__ bih2,
                              const float* __restrict__ bhh2,
                              unsigned short* __restrict__ Bhi1, unsigned short* __restrict__ Blo1,
                              unsigned short* __restrict__ Bhi2, unsigned short* __restrict__ Blo2,
                              int* __restrict__ counts, int n) {
  if ((int)blockIdx.x >= 128) {
    int i = ((int)blockIdx.x - 128) * SB + threadIdx.x;
    if (i < n) counts[i] = 0;
    return;
  }
  int t = blockIdx.x * 256 + threadIdx.x;     // 0..32767
  int layer = t >> 14;
  int tt = t & 16383;
  const float* W0  = layer ? W02  : W01;
  const float* wih = layer ? wih2 : wih1;
  const float* whh = layer ? whh2 : whh1;
  const float* bih = layer ? bih2 : bih1;
  const float* bhh = layer ? bhh2 : bhh1;
  unsigned short* Bhi = layer ? Bhi2 : Bhi1;
  unsigned short* Blo = layer ? Blo2 : Blo1;
  int i = tt >> 7, j = tt & 127;      // i = k (feature) index, j = w_col index
  const float4* w0r = (const float4*)(W0 + (size_t)i * F);
  float gi[3], gh[3];
#pragma unroll
  for (int g = 0; g < 3; ++g) {
    const float4* wr = (const float4*)(wih + (size_t)(g * F + j) * F);
    const float4* hr = (const float4*)(whh + (size_t)(g * F + j) * F);
    float si = 0.f, sh = 0.f;
    for (int k = 0; k < F / 4; ++k) {
      float4 a = w0r[k];
      float4 b = wr[k];
      float4 c = hr[k];
      si += a.x * b.x + a.y * b.y + a.z * b.z + a.w * b.w;
      sh += a.x * c.x + a.y * c.y + a.z * c.z + a.w * c.w;
    }
    gi[g] = si + bih[g * F + j];
    gh[g] = sh + bhh[g * F + j];
  }
  float r = 1.0f / (1.0f + expf(-(gi[0] + gh[0])));
  float z = 1.0f / (1.0f + expf(-(gi[1] + gh[1])));
  float nn = tanhf(gi[2] + r * gh[2]);
  float val = (1.0f - z) * nn + z * W0[(size_t)i * F + j];

  unsigned u = __float_as_uint(val);
  unsigned short hi = (unsigned short)(u >> 16);
  float lo_f = val - __uint_as_float(u & 0xFFFF0000u);
  unsigned short lo = bf16_rne(lo_f);
  int kstep = i >> 5, kl = i & 31;
  int lane = (kl >> 3) * 16 + (j & 15);
  int tile = j >> 4;
  int idx = ((kstep * 8 + tile) * 64 + lane) * 8 + (kl & 7);
  Bhi[idx] = hi;
  Blo[idx] = lo;
}

// ---------------- CSR build ----------------
__global__ void count_rank_k(const int* __restrict__ dst, int* __restrict__ counts,
                             int* __restrict__ rank, int E) {
  int e = blockIdx.x * blockDim.x + threadIdx.x;
  if (e < E) rank[e] = atomicAdd(&counts[dst[e]], 1);
}

__global__ void scan_local_k(const int* __restrict__ counts, int* __restrict__ incl,
                             int* __restrict__ blocksum, int n) {
  __shared__ int sh[SB];
  int gid = blockIdx.x * SB + threadIdx.x;
  int v = (gid < n) ? counts[gid] : 0;
  sh[threadIdx.x] = v;
  __syncthreads();
  for (int off = 1; off < SB; off <<= 1) {
    int t = 0;
    if ((int)threadIdx.x >= off) t = sh[threadIdx.x - off];
    __syncthreads();
    if ((int)threadIdx.x >= off) sh[threadIdx.x] += t;
    __syncthreads();
  }
  if (gid < n) incl[gid] = sh[threadIdx.x];
  if (threadIdx.x == SB - 1) blocksum[blockIdx.x] = sh[SB - 1];
}

// scan_finish with in-kernel blocksum scan.
__global__ void scan_finish_k(const int* __restrict__ counts, const int* __restrict__ incl,
                              const int* __restrict__ blocksum, int* __restrict__ rowptr,
                              float* __restrict__ dinv, int n, int nb) {
  __shared__ int sh[SB];
  __shared__ int orig[SB];
  int v = ((int)threadIdx.x < nb) ? blocksum[threadIdx.x] : 0;
  sh[threadIdx.x] = v;
  orig[threadIdx.x] = v;
  __syncthreads();
  for (int off = 1; off < SB; off <<= 1) {
    int t = 0;
    if ((int)threadIdx.x >= off) t = sh[threadIdx.x - off];
    __syncthreads();
    if ((int)threadIdx.x >= off) sh[threadIdx.x] += t;
    __syncthreads();
  }
  int myoff = sh[blockIdx.x] - orig[blockIdx.x];   // exclusive prefix for this block
  int gid = blockIdx.x * SB + threadIdx.x;
  if (gid >= n) return;
  int c = counts[gid];
  int inc = myoff + incl[gid];
  rowptr[gid] = inc - c;
  dinv[gid] = rsqrtf((float)c + 1.0f);
  if (gid == n - 1) rowptr[n] = inc;
}

// ---------------- device bodies: fill + MFMA gemm (shared by fused dispatch) ----------------
// fill stores PRE-SHIFTED src (src<<8 = byte offset of the 256B row) so the
// gather needs no per-load shift.
__device__ __forceinline__ void fill_body(int bid, const int* __restrict__ src,
                                          const int* __restrict__ dst,
                                          const int* __restrict__ rank,
                                          const int* __restrict__ rowptr,
                                          int* __restrict__ csr_src, int E) {
  int e = bid * 256 + (int)threadIdx.x;
  if (e < E) {
    int d = dst[e];
    csr_src[rowptr[d] + rank[e]] = src[e] << 8;
  }
}

// Transposed MFMA: D = W' (A) x X^T (B); lane owns x_row = lane&15, 4 consecutive
// w_cols per tile; epilogue packs linear col pairs; output row-major (row*64 uints).
// Split-bf16: X@W = Xhi@Whi + Xlo@Whi + Xhi@Wlo.
__device__ __forceinline__ void gemm_body(int bid, const float* __restrict__ X,
                                          const unsigned short* __restrict__ Bhi,
                                          const unsigned short* __restrict__ Blo,
                                          const float* __restrict__ dinv,
                                          unsigned* __restrict__ Y, int nrows) {
  int wid = bid * 4 + ((int)threadIdx.x >> 6);
  int lane = threadIdx.x & 63;
  int ng = (nrows + 15) >> 4;
  if (wid >= ng) return;
  int g = __builtin_amdgcn_readfirstlane(wid);
  int q = lane >> 4, m = lane & 15;
  int rowA = g * 16 + m;
  if (rowA >= nrows) rowA = nrows - 1;

  f32x4 acc[8];
#pragma unroll
  for (int t = 0; t < 8; ++t) { acc[t].x = 0.f; acc[t].y = 0.f; acc[t].z = 0.f; acc[t].w = 0.f; }

#pragma unroll
  for (int s = 0; s < 4; ++s) {
    const float* xp = X + (size_t)rowA * F + s * 32 + q * 8;
    float4 xa = *(const float4*)xp;
    float4 xb = *(const float4*)(xp + 4);
    float xv[8] = {xa.x, xa.y, xa.z, xa.w, xb.x, xb.y, xb.z, xb.w};
    bf16x8 xhi, xlo;
#pragma unroll
    for (int j = 0; j < 8; ++j) {
      unsigned u = __float_as_uint(xv[j]);
      xhi[j] = (short)(u >> 16);
      float lf = xv[j] - __uint_as_float(u & 0xFFFF0000u);
      xlo[j] = (short)bf16_rne(lf);
    }
#pragma unroll
    for (int t = 0; t < 8; ++t) {
      size_t boff = ((size_t)(s * 8 + t) * 64 + lane) * 8;
      bf16x8 wh = *(const bf16x8*)(Bhi + boff);
      bf16x8 wl = *(const bf16x8*)(Blo + boff);
      acc[t] = __builtin_amdgcn_mfma_f32_16x16x32_bf16(wh, xhi, acc[t], 0, 0, 0);
      acc[t] = __builtin_amdgcn_mfma_f32_16x16x32_bf16(wh, xlo, acc[t], 0, 0, 0);
      acc[t] = __builtin_amdgcn_mfma_f32_16x16x32_bf16(wl, xhi, acc[t], 0, 0, 0);
    }
  }

  int row = g * 16 + m;
  if (row < nrows) {
    float dd = dinv[row];
    unsigned* yr = Y + (size_t)row * 64 + q * 2;
#pragma unroll
    for (int t = 0; t < 8; ++t) {
      uint2 o;
      o.x = pack_bf16x2(dd * acc[t].x, dd * acc[t].y);
      o.y = pack_bf16x2(dd * acc[t].z, dd * acc[t].w);
      *(uint2*)(yr + t * 8) = o;
    }
  }
}

__global__ void gemm_mfma_k(const float* __restrict__ X,
                            const unsigned short* __restrict__ Bhi,
                            const unsigned short* __restrict__ Blo,
                            const float* __restrict__ dinv, unsigned* __restrict__ Y,
                            int nrows) {
  gemm_body(blockIdx.x, X, Bhi, Blo, dinv, Y, nrows);
}

// fused: blocks [0, ngemm) do layer-1 gemm; [ngemm, ...) do csr fill.
__global__ void fill_gemm_k(const float* __restrict__ X,
                            const unsigned short* __restrict__ Bhi,
                            const unsigned short* __restrict__ Blo,
                            const float* __restrict__ dinv, unsigned* __restrict__ Y,
                            int nrows, int ngemm,
                            const int* __restrict__ src, const int* __restrict__ dst,
                            const int* __restrict__ rank, const int* __restrict__ rowptr,
                            int* __restrict__ csr_src, int E) {
  if ((int)blockIdx.x < ngemm)
    gemm_body(blockIdx.x, X, Bhi, Blo, dinv, Y, nrows);
  else
    fill_body((int)blockIdx.x - ngemm, src, dst, rank, rowptr, csr_src, E);
}

// ---------------- gather aggregation v6: half-wave, 16-edge unroll, 3 VALU/edge ----
// One wave per node. Lanes 0-31 take even edges, 32-63 odd edges; lane (half,hm)
// loads uint2 = cols 4hm..4hm+3 of its edge's row. csr entries are PRE-SHIFTED
// byte offsets -> per load: cndmask + v_or only. Dirty unpack: shl + pk_add per
// uint. Epilogue: 4x shfl_xor(32).
template <bool FUSE_LOGITS>
__global__ void agg_bf16_k(const int* __restrict__ rowptr, const int* __restrict__ csr_src,
                           const float* __restrict__ dinv, const unsigned* __restrict__ xwp,
                           float* __restrict__ hout,
                           const float* __restrict__ lw, const float* __restrict__ lb,
                           float* __restrict__ outp, int n) {
  int wave = (int)((blockIdx.x * blockDim.x + threadIdx.x) >> 6);
  int lane = threadIdx.x & 63;
  if (wave >= n) return;
  int node = __builtin_amdgcn_readfirstlane(wave);
  int half = lane >> 5, hm = lane & 31;
  float dd = dinv[node];
  const char* __restrict__ cb = (const char*)xwp;   // row = 256 bytes
  unsigned loff = (unsigned)(hm << 3);
  f32x2 acc0 = {0.f, 0.f}, acc1 = {0.f, 0.f};
  f32x2 bcc0 = {0.f, 0.f}, bcc1 = {0.f, 0.f};

  // self-loop (lower half only; upper half contributes 0)
  {
    uint2 u = *(const uint2*)(cb + ((((unsigned)node) << 8) | loff));
    if (half) { u.x = 0u; u.y = 0u; }
    acc0 += unpk2(u.x);
    acc1 += unpk2(u.y);
  }

  int b = rowptr[node], e = rowptr[node + 1];
  int i = b;
  // 16-edge main loop: 8 dwordx2 loads (4 KB) in flight per wave
  for (; i + 16 <= e; i += 16) {
    int s0 = csr_src[i + 0],  s1 = csr_src[i + 1],  s2 = csr_src[i + 2],  s3 = csr_src[i + 3];
    int s4 = csr_src[i + 4],  s5 = csr_src[i + 5],  s6 = csr_src[i + 6],  s7 = csr_src[i + 7];
    int s8 = csr_src[i + 8],  s9 = csr_src[i + 9],  sA = csr_src[i + 10], sB = csr_src[i + 11];
    int sC = csr_src[i + 12], sD = csr_src[i + 13], sE = csr_src[i + 14], sF = csr_src[i + 15];
    unsigned o0 = ((unsigned)(half ? s1 : s0)) | loff;
    unsigned o1 = ((unsigned)(half ? s3 : s2)) | loff;
    unsigned o2 = ((unsigned)(half ? s5 : s4)) | loff;
    unsigned o3 = ((unsigned)(half ? s7 : s6)) | loff;
    unsigned o4 = ((unsigned)(half ? s9 : s8)) | loff;
    unsigned o5 = ((unsigned)(half ? sB : sA)) | loff;
    unsigned o6 = ((unsigned)(half ? sD : sC)) | loff;
    unsigned o7 = ((unsigned)(half ? sF : sE)) | loff;
    uint2 u0 = *(const uint2*)(cb + o0);
    uint2 u1 = *(const uint2*)(cb + o1);
    uint2 u2 = *(const uint2*)(cb + o2);
    uint2 u3 = *(const uint2*)(cb + o3);
    uint2 u4 = *(const uint2*)(cb + o4);
    uint2 u5 = *(const uint2*)(cb + o5);
    uint2 u6 = *(const uint2*)(cb + o6);
    uint2 u7 = *(const uint2*)(cb + o7);
    acc0 += unpk2(u0.x); acc1 += unpk2(u0.y);
    bcc0 += unpk2(u1.x); bcc1 += unpk2(u1.y);
    acc0 += unpk2(u2.x); acc1 += unpk2(u2.y);
    bcc0 += unpk2(u3.x); bcc1 += unpk2(u3.y);
    acc0 += unpk2(u4.x); acc1 += unpk2(u4.y);
    bcc0 += unpk2(u5.x); bcc1 += unpk2(u5.y);
    acc0 += unpk2(u6.x); acc1 += unpk2(u6.y);
    bcc0 += unpk2(u7.x); bcc1 += unpk2(u7.y);
  }
  // 8-edge tail
  for (; i + 8 <= e; i += 8) {
    int s0 = csr_src[i + 0], s1 = csr_src[i + 1], s2 = csr_src[i + 2], s3 = csr_src[i + 3];
    int s4 = csr_src[i + 4], s5 = csr_src[i + 5], s6 = csr_src[i + 6], s7 = csr_src[i + 7];
    unsigned o0 = ((unsigned)(half ? s1 : s0)) | loff;
    unsigned o1 = ((unsigned)(half ? s3 : s2)) | loff;
    unsigned o2 = ((unsigned)(half ? s5 : s4)) | loff;
    unsigned o3 = ((unsigned)(half ? s7 : s6)) | loff;
    uint2 u0 = *(const uint2*)(cb + o0);
    uint2 u1 = *(const uint2*)(cb + o1);
    uint2 u2 = *(const uint2*)(cb + o2);
    uint2 u3 = *(const uint2*)(cb + o3);
    acc0 += unpk2(u0.x); acc1 += unpk2(u0.y);
    bcc0 += unpk2(u1.x); bcc1 += unpk2(u1.y);
    acc0 += unpk2(u2.x); acc1 += unpk2(u2.y);
    bcc0 += unpk2(u3.x); bcc1 += unpk2(u3.y);
  }
  for (; i + 2 <= e; i += 2) {
    int s0 = csr_src[i], s1 = csr_src[i + 1];
    unsigned o = ((unsigned)(half ? s1 : s0)) | loff;
    uint2 u = *(const uint2*)(cb + o);
    acc0 += unpk2(u.x);
    acc1 += unpk2(u.y);
  }
  if (i < e) {
    int s = csr_src[i];
    uint2 u = *(const uint2*)(cb + (((unsigned)s) | loff));
    if (half) { u.x = 0u; u.y = 0u; }
    acc0 += unpk2(u.x);
    acc1 += unpk2(u.y);
  }
  acc0 += bcc0;
  acc1 += bcc1;

  // combine the two halves (both end up with the full sum)
  acc0.x += __shfl_xor(acc0.x, 32);
  acc0.y += __shfl_xor(acc0.y, 32);
  acc1.x += __shfl_xor(acc1.x, 32);
  acc1.y += __shfl_xor(acc1.y, 32);

  float h0 = fmaxf(dd * acc0.x, 0.f);
  float h1 = fmaxf(dd * acc0.y, 0.f);
  float h2 = fmaxf(dd * acc1.x, 0.f);
  float h3 = fmaxf(dd * acc1.y, 0.f);

  if (!FUSE_LOGITS) {
    if (half == 0) {
      *(float4*)(hout + (size_t)node * F + hm * 4) = make_float4(h0, h1, h2, h3);
    }
  } else {
    float acc[C_OUT];
#pragma unroll
    for (int c = 0; c < C_OUT; ++c) {
      float4 w = *(const float4*)(lw + (size_t)c * F + hm * 4);
      float v = h0 * w.x + h1 * w.y + h2 * w.z + h3 * w.w;
      v += __shfl_xor(v, 1); v += __shfl_xor(v, 2);
      v += __shfl_xor(v, 4); v += __shfl_xor(v, 8);
      v += __shfl_xor(v, 16);
      acc[c] = v + lb[c];
    }
    float mx = acc[0];
#pragma unroll
    for (int c = 1; c < C_OUT; ++c) mx = fmaxf(mx, acc[c]);
    float s = 0.f;
#pragma unroll
    for (int c = 0; c < C_OUT; ++c) s += expf(acc[c] - mx);
    float lse = mx + logf(s);
#pragma unroll
    for (int c = 0; c < C_OUT; ++c)
      if (lane == c) outp[(size_t)node * C_OUT + c] = acc[c] - lse;
  }
}

extern "C" void kernel_launch(void* const* d_in, const int* in_sizes, int n_in,
                              void* d_out, int out_size, void* d_ws, size_t ws_size,
                              hipStream_t stream) {
  const float* x    = (const float*)d_in[0];
  const int*   ei   = (const int*)d_in[1];
  const float* W1   = (const float*)d_in[2];
  const float* wih1 = (const float*)d_in[3];
  const float* whh1 = (const float*)d_in[4];
  const float* bih1 = (const float*)d_in[5];
  const float* bhh1 = (const float*)d_in[6];
  const float* W2   = (const float*)d_in[7];
  const float* wih2 = (const float*)d_in[8];
  const float* whh2 = (const float*)d_in[9];
  const float* bih2 = (const float*)d_in[10];
  const float* bhh2 = (const float*)d_in[11];
  const float* lw   = (const float*)d_in[12];
  const float* lb   = (const float*)d_in[13];
  float* out = (float*)d_out;

  int N = in_sizes[0] / F;
  int E = in_sizes[1] / 2;
  const int* src = ei;
  const int* dst = ei + E;
  int nb = (N + SB - 1) / SB;   // 196 for N=50000 (must be <= 256)
  int ng = (N + 15) / 16;       // 16-row groups
  int ngemm = (ng + 3) / 4;     // gemm blocks (4 waves each)
  int nfill = (E + 255) / 256;  // fill blocks

  float* ws   = (float*)d_ws;
  unsigned* bufA = (unsigned*)ws;          // N*64 uints (linear bf16x2 xw')
  float* bufB = ws + (size_t)N * F / 2;    // N*F floats (h)
  float* dinv = bufB + (size_t)N * F;      // N
  unsigned short* Bhi1 = (unsigned short*)(dinv + N);  // 16384 each
  unsigned short* Blo1 = Bhi1 + F * F;
  unsigned short* Bhi2 = Blo1 + F * F;
  unsigned short* Blo2 = Bhi2 + F * F;
  int* counts = (int*)(Blo2 + F * F);      // N
  int* rowptr = counts + N;                // N+1
  int* rank   = rowptr + N + 1;            // E
  int* incl   = rank + E;                  // N
  int* blocksum = incl + N;                // nb (<=256)
  int* csr_src = blocksum + 256;           // E

  // evolve weights (both layers, packed bf16 hi/lo fragments) + zero counts
  gru_evolve2_k<<<128 + nb, 256, 0, stream>>>(W1, wih1, whh1, bih1, bhh1,
                                              W2, wih2, whh2, bih2, bhh2,
                                              Bhi1, Blo1, Bhi2, Blo2, counts, N);

  // ----- CSR build + normalization (parallel scan) -----
  count_rank_k<<<(E + 255) / 256, 256, 0, stream>>>(dst, counts, rank, E);
  scan_local_k<<<nb, SB, 0, stream>>>(counts, incl, blocksum, N);
  scan_finish_k<<<nb, SB, 0, stream>>>(counts, incl, blocksum, rowptr, dinv, N, nb);

  // ----- layer 1 gemm + csr fill (independent; fused dispatch) -----
  fill_gemm_k<<<ngemm + nfill, 256, 0, stream>>>(x, Bhi1, Blo1, dinv, bufA, N, ngemm,
                                                 src, dst, rank, rowptr, csr_src, E);
  agg_bf16_k<false><<<(N + 3) / 4, 256, 0, stream>>>(rowptr, csr_src, dinv, bufA, bufB,
                                                     nullptr, nullptr, nullptr, N);

  // ----- layer 2 (logits fused) -----
  gemm_mfma_k<<<ngemm, 256, 0, stream>>>(bufB, Bhi2, Blo2, dinv, bufA, N);
  agg_bf16_k<true><<<(N + 3) / 4, 256, 0, stream>>>(rowptr, csr_src, dinv, bufA, nullptr,
                                                    lw, lb, out, N);
}

// Round 13
// 263.536 us; speedup vs baseline: 1.0471x; 1.0471x over previous
//
#include <hip/hip_runtime.h>
#include <cstddef>
#include <cstdint>

#define F 128
#define C_OUT 10
#define SB 256   // scan block size

typedef short bf16x8 __attribute__((ext_vector_type(8)));
typedef float f32x4  __attribute__((ext_vector_type(4)));
typedef float f32x2  __attribute__((ext_vector_type(2)));

// ---- bf16 helpers (weights path) ----
__device__ __forceinline__ unsigned short bf16_rne(float f) {
  unsigned u = __float_as_uint(f);
  return (unsigned short)((u + 0x7FFFu + ((u >> 16) & 1u)) >> 16);
}

// ---------------- GRU weight evolution (both layers) + zero counts ----------------
__global__ void gru_evolve2_k(const float* __restrict__ W01, const float* __restrict__ wih1,
                              const float* __restrict__ whh1, const float* __restrict__ bih1,
                              const float* __restrict__ bhh1,
                              const float* __restrict__ W02, const float* __restrict__ wih2,
                              const float* __restrict__ whh2, const float* __restrict__ bih2,
                              const float* __restrict__ bhh2,
                              unsigned short* __restrict__ Bhi1, unsigned short* __restrict__ Blo1,
                              unsigned short* __restrict__ Bhi2, unsigned short* __restrict__ Blo2,
                              int* __restrict__ counts, int n) {
  if ((int)blockIdx.x >= 128) {
    int i = ((int)blockIdx.x - 128) * SB + threadIdx.x;
    if (i < n) counts[i] = 0;
    return;
  }
  int t = blockIdx.x * 256 + threadIdx.x;     // 0..32767
  int layer = t >> 14;
  int tt = t & 16383;
  const float* W0  = layer ? W02  : W01;
  const float* wih = layer ? wih2 : wih1;
  const float* whh = layer ? whh2 : whh1;
  const float* bih = layer ? bih2 : bih1;
  const float* bhh = layer ? bhh2 : bhh1;
  unsigned short* Bhi = layer ? Bhi2 : Bhi1;
  unsigned short* Blo = layer ? Blo2 : Blo1;
  int i = tt >> 7, j = tt & 127;      // i = k (feature) index, j = w_col index
  const float4* w0r = (const float4*)(W0 + (size_t)i * F);
  float gi[3], gh[3];
#pragma unroll
  for (int g = 0; g < 3; ++g) {
    const float4* wr = (const float4*)(wih + (size_t)(g * F + j) * F);
    const float4* hr = (const float4*)(whh + (size_t)(g * F + j) * F);
    float si = 0.f, sh = 0.f;
    for (int k = 0; k < F / 4; ++k) {
      float4 a = w0r[k];
      float4 b = wr[k];
      float4 c = hr[k];
      si += a.x * b.x + a.y * b.y + a.z * b.z + a.w * b.w;
      sh += a.x * c.x + a.y * c.y + a.z * c.z + a.w * c.w;
    }
    gi[g] = si + bih[g * F + j];
    gh[g] = sh + bhh[g * F + j];
  }
  float r = 1.0f / (1.0f + expf(-(gi[0] + gh[0])));
  float z = 1.0f / (1.0f + expf(-(gi[1] + gh[1])));
  float nn = tanhf(gi[2] + r * gh[2]);
  float val = (1.0f - z) * nn + z * W0[(size_t)i * F + j];

  unsigned u = __float_as_uint(val);
  unsigned short hi = (unsigned short)(u >> 16);
  float lo_f = val - __uint_as_float(u & 0xFFFF0000u);
  unsigned short lo = bf16_rne(lo_f);
  int kstep = i >> 5, kl = i & 31;
  int lane = (kl >> 3) * 16 + (j & 15);
  int tile = j >> 4;
  int idx = ((kstep * 8 + tile) * 64 + lane) * 8 + (kl & 7);
  Bhi[idx] = hi;
  Blo[idx] = lo;
}

// ---------------- CSR build ----------------
__global__ void count_rank_k(const int* __restrict__ dst, int* __restrict__ counts,
                             int* __restrict__ rank, int E) {
  int e = blockIdx.x * blockDim.x + threadIdx.x;
  if (e < E) rank[e] = atomicAdd(&counts[dst[e]], 1);
}

__global__ void scan_local_k(const int* __restrict__ counts, int* __restrict__ incl,
                             int* __restrict__ blocksum, int n) {
  __shared__ int sh[SB];
  int gid = blockIdx.x * SB + threadIdx.x;
  int v = (gid < n) ? counts[gid] : 0;
  sh[threadIdx.x] = v;
  __syncthreads();
  for (int off = 1; off < SB; off <<= 1) {
    int t = 0;
    if ((int)threadIdx.x >= off) t = sh[threadIdx.x - off];
    __syncthreads();
    if ((int)threadIdx.x >= off) sh[threadIdx.x] += t;
    __syncthreads();
  }
  if (gid < n) incl[gid] = sh[threadIdx.x];
  if (threadIdx.x == SB - 1) blocksum[blockIdx.x] = sh[SB - 1];
}

// scan_finish with in-kernel blocksum scan.
__global__ void scan_finish_k(const int* __restrict__ counts, const int* __restrict__ incl,
                              const int* __restrict__ blocksum, int* __restrict__ rowptr,
                              float* __restrict__ dinv, int n, int nb) {
  __shared__ int sh[SB];
  __shared__ int orig[SB];
  int v = ((int)threadIdx.x < nb) ? blocksum[threadIdx.x] : 0;
  sh[threadIdx.x] = v;
  orig[threadIdx.x] = v;
  __syncthreads();
  for (int off = 1; off < SB; off <<= 1) {
    int t = 0;
    if ((int)threadIdx.x >= off) t = sh[threadIdx.x - off];
    __syncthreads();
    if ((int)threadIdx.x >= off) sh[threadIdx.x] += t;
    __syncthreads();
  }
  int myoff = sh[blockIdx.x] - orig[blockIdx.x];   // exclusive prefix for this block
  int gid = blockIdx.x * SB + threadIdx.x;
  if (gid >= n) return;
  int c = counts[gid];
  int inc = myoff + incl[gid];
  rowptr[gid] = inc - c;
  dinv[gid] = rsqrtf((float)c + 1.0f);
  if (gid == n - 1) rowptr[n] = inc;
}

// ---------------- device bodies: fill + MFMA gemm (shared by fused dispatch) ----------------
// fill stores PRE-SHIFTED src (src<<7 = byte offset of the 128B fp8 row).
__device__ __forceinline__ void fill_body(int bid, const int* __restrict__ src,
                                          const int* __restrict__ dst,
                                          const int* __restrict__ rank,
                                          const int* __restrict__ rowptr,
                                          int* __restrict__ csr_src, int E) {
  int e = bid * 256 + (int)threadIdx.x;
  if (e < E) {
    int d = dst[e];
    csr_src[rowptr[d] + rank[e]] = src[e] << 7;
  }
}

// Transposed MFMA: D = W' (A) x X^T (B); lane owns x_row = lane&15, 4 consecutive
// w_cols per tile. Epilogue: Y'[row] = fp8_e4m3(dinv[row] * (X@W)[row]) -- one
// 128-byte line per row (HW cvt_pk_fp8_f32 encode; agg decodes with the matching
// cvt_pk_f32_fp8, so round-trip is format-consistent).
// Split-bf16 MFMA: X@W = Xhi@Whi + Xlo@Whi + Xhi@Wlo (fp32-grade product).
__device__ __forceinline__ void gemm_body(int bid, const float* __restrict__ X,
                                          const unsigned short* __restrict__ Bhi,
                                          const unsigned short* __restrict__ Blo,
                                          const float* __restrict__ dinv,
                                          unsigned* __restrict__ Y, int nrows) {
  int wid = bid * 4 + ((int)threadIdx.x >> 6);
  int lane = threadIdx.x & 63;
  int ng = (nrows + 15) >> 4;
  if (wid >= ng) return;
  int g = __builtin_amdgcn_readfirstlane(wid);
  int q = lane >> 4, m = lane & 15;
  int rowA = g * 16 + m;
  if (rowA >= nrows) rowA = nrows - 1;

  f32x4 acc[8];
#pragma unroll
  for (int t = 0; t < 8; ++t) { acc[t].x = 0.f; acc[t].y = 0.f; acc[t].z = 0.f; acc[t].w = 0.f; }

#pragma unroll
  for (int s = 0; s < 4; ++s) {
    const float* xp = X + (size_t)rowA * F + s * 32 + q * 8;
    float4 xa = *(const float4*)xp;
    float4 xb = *(const float4*)(xp + 4);
    float xv[8] = {xa.x, xa.y, xa.z, xa.w, xb.x, xb.y, xb.z, xb.w};
    bf16x8 xhi, xlo;
#pragma unroll
    for (int j = 0; j < 8; ++j) {
      unsigned u = __float_as_uint(xv[j]);
      xhi[j] = (short)(u >> 16);
      float lf = xv[j] - __uint_as_float(u & 0xFFFF0000u);
      xlo[j] = (short)bf16_rne(lf);
    }
#pragma unroll
    for (int t = 0; t < 8; ++t) {
      size_t boff = ((size_t)(s * 8 + t) * 64 + lane) * 8;
      bf16x8 wh = *(const bf16x8*)(Bhi + boff);
      bf16x8 wl = *(const bf16x8*)(Blo + boff);
      acc[t] = __builtin_amdgcn_mfma_f32_16x16x32_bf16(wh, xhi, acc[t], 0, 0, 0);
      acc[t] = __builtin_amdgcn_mfma_f32_16x16x32_bf16(wh, xlo, acc[t], 0, 0, 0);
      acc[t] = __builtin_amdgcn_mfma_f32_16x16x32_bf16(wl, xhi, acc[t], 0, 0, 0);
    }
  }

  int row = g * 16 + m;
  if (row < nrows) {
    float dd = dinv[row];
    // lane q owns cols {t*16 + q*4 .. +3}; dword index = t*4 + q; row = 32 dwords
    unsigned* yr = Y + (size_t)row * 32 + q;
#pragma unroll
    for (int t = 0; t < 8; ++t) {
      int p = __builtin_amdgcn_cvt_pk_fp8_f32(dd * acc[t].x, dd * acc[t].y, 0, false);
      p = __builtin_amdgcn_cvt_pk_fp8_f32(dd * acc[t].z, dd * acc[t].w, p, true);
      yr[t * 4] = (unsigned)p;
    }
  }
}

__global__ void gemm_mfma_k(const float* __restrict__ X,
                            const unsigned short* __restrict__ Bhi,
                            const unsigned short* __restrict__ Blo,
                            const float* __restrict__ dinv, unsigned* __restrict__ Y,
                            int nrows) {
  gemm_body(blockIdx.x, X, Bhi, Blo, dinv, Y, nrows);
}

// fused: blocks [0, ngemm) do layer-1 gemm; [ngemm, ...) do csr fill.
__global__ void fill_gemm_k(const float* __restrict__ X,
                            const unsigned short* __restrict__ Bhi,
                            const unsigned short* __restrict__ Blo,
                            const float* __restrict__ dinv, unsigned* __restrict__ Y,
                            int nrows, int ngemm,
                            const int* __restrict__ src, const int* __restrict__ dst,
                            const int* __restrict__ rank, const int* __restrict__ rowptr,
                            int* __restrict__ csr_src, int E) {
  if ((int)blockIdx.x < ngemm)
    gemm_body(blockIdx.x, X, Bhi, Blo, dinv, Y, nrows);
  else
    fill_body((int)blockIdx.x - ngemm, src, dst, rank, rowptr, csr_src, E);
}

// ---------------- gather aggregation v7: fp8 rows (128 B), half-wave ----------------
// One wave per node. Lanes 0-31 even edges, 32-63 odd edges; lane (half,hm) loads
// one dword = 4 fp8 cols {4hm..4hm+3} of its edge's row. csr entries PRE-SHIFTED
// byte offsets (row<<7). Decode via HW cvt_pk_f32_fp8. Epilogue: 4x shfl_xor(32).
template <bool FUSE_LOGITS>
__global__ void agg_fp8_k(const int* __restrict__ rowptr, const int* __restrict__ csr_src,
                          const float* __restrict__ dinv, const unsigned* __restrict__ xwp,
                          float* __restrict__ hout,
                          const float* __restrict__ lw, const float* __restrict__ lb,
                          float* __restrict__ outp, int n) {
  int wave = (int)((blockIdx.x * blockDim.x + threadIdx.x) >> 6);
  int lane = threadIdx.x & 63;
  if (wave >= n) return;
  int node = __builtin_amdgcn_readfirstlane(wave);
  int half = lane >> 5, hm = lane & 31;
  float dd = dinv[node];
  const char* __restrict__ cb = (const char*)xwp;   // row = 128 bytes
  unsigned loff = (unsigned)(hm << 2);
  f32x2 acc0 = {0.f, 0.f}, acc1 = {0.f, 0.f};
  f32x2 bcc0 = {0.f, 0.f}, bcc1 = {0.f, 0.f};

#define DEC(U, A, B)                                           \
  do {                                                         \
    (A) += __builtin_amdgcn_cvt_pk_f32_fp8((int)(U), false);   \
    (B) += __builtin_amdgcn_cvt_pk_f32_fp8((int)(U), true);    \
  } while (0)

  // self-loop (lower half only; upper half contributes 0)
  {
    unsigned u = *(const unsigned*)(cb + ((((unsigned)node) << 7) | loff));
    if (half) u = 0u;
    DEC(u, acc0, acc1);
  }

  int b = rowptr[node], e = rowptr[node + 1];
  int i = b;
  // 16-edge main loop: 8 dword loads in flight per wave
  for (; i + 16 <= e; i += 16) {
    int s0 = csr_src[i + 0],  s1 = csr_src[i + 1],  s2 = csr_src[i + 2],  s3 = csr_src[i + 3];
    int s4 = csr_src[i + 4],  s5 = csr_src[i + 5],  s6 = csr_src[i + 6],  s7 = csr_src[i + 7];
    int s8 = csr_src[i + 8],  s9 = csr_src[i + 9],  sA = csr_src[i + 10], sB = csr_src[i + 11];
    int sC = csr_src[i + 12], sD = csr_src[i + 13], sE = csr_src[i + 14], sF = csr_src[i + 15];
    unsigned o0 = ((unsigned)(half ? s1 : s0)) | loff;
    unsigned o1 = ((unsigned)(half ? s3 : s2)) | loff;
    unsigned o2 = ((unsigned)(half ? s5 : s4)) | loff;
    unsigned o3 = ((unsigned)(half ? s7 : s6)) | loff;
    unsigned o4 = ((unsigned)(half ? s9 : s8)) | loff;
    unsigned o5 = ((unsigned)(half ? sB : sA)) | loff;
    unsigned o6 = ((unsigned)(half ? sD : sC)) | loff;
    unsigned o7 = ((unsigned)(half ? sF : sE)) | loff;
    unsigned u0 = *(const unsigned*)(cb + o0);
    unsigned u1 = *(const unsigned*)(cb + o1);
    unsigned u2 = *(const unsigned*)(cb + o2);
    unsigned u3 = *(const unsigned*)(cb + o3);
    unsigned u4 = *(const unsigned*)(cb + o4);
    unsigned u5 = *(const unsigned*)(cb + o5);
    unsigned u6 = *(const unsigned*)(cb + o6);
    unsigned u7 = *(const unsigned*)(cb + o7);
    DEC(u0, acc0, acc1);
    DEC(u1, bcc0, bcc1);
    DEC(u2, acc0, acc1);
    DEC(u3, bcc0, bcc1);
    DEC(u4, acc0, acc1);
    DEC(u5, bcc0, bcc1);
    DEC(u6, acc0, acc1);
    DEC(u7, bcc0, bcc1);
  }
  // 8-edge tail
  for (; i + 8 <= e; i += 8) {
    int s0 = csr_src[i + 0], s1 = csr_src[i + 1], s2 = csr_src[i + 2], s3 = csr_src[i + 3];
    int s4 = csr_src[i + 4], s5 = csr_src[i + 5], s6 = csr_src[i + 6], s7 = csr_src[i + 7];
    unsigned o0 = ((unsigned)(half ? s1 : s0)) | loff;
    unsigned o1 = ((unsigned)(half ? s3 : s2)) | loff;
    unsigned o2 = ((unsigned)(half ? s5 : s4)) | loff;
    unsigned o3 = ((unsigned)(half ? s7 : s6)) | loff;
    unsigned u0 = *(const unsigned*)(cb + o0);
    unsigned u1 = *(const unsigned*)(cb + o1);
    unsigned u2 = *(const unsigned*)(cb + o2);
    unsigned u3 = *(const unsigned*)(cb + o3);
    DEC(u0, acc0, acc1);
    DEC(u1, bcc0, bcc1);
    DEC(u2, acc0, acc1);
    DEC(u3, bcc0, bcc1);
  }
  for (; i + 2 <= e; i += 2) {
    int s0 = csr_src[i], s1 = csr_src[i + 1];
    unsigned o = ((unsigned)(half ? s1 : s0)) | loff;
    unsigned u = *(const unsigned*)(cb + o);
    DEC(u, acc0, acc1);
  }
  if (i < e) {
    int s = csr_src[i];
    unsigned u = *(const unsigned*)(cb + (((unsigned)s) | loff));
    if (half) u = 0u;
    DEC(u, acc0, acc1);
  }
#undef DEC
  acc0 += bcc0;
  acc1 += bcc1;

  // combine the two halves (both end up with the full sum)
  acc0.x += __shfl_xor(acc0.x, 32);
  acc0.y += __shfl_xor(acc0.y, 32);
  acc1.x += __shfl_xor(acc1.x, 32);
  acc1.y += __shfl_xor(acc1.y, 32);

  float h0 = fmaxf(dd * acc0.x, 0.f);
  float h1 = fmaxf(dd * acc0.y, 0.f);
  float h2 = fmaxf(dd * acc1.x, 0.f);
  float h3 = fmaxf(dd * acc1.y, 0.f);

  if (!FUSE_LOGITS) {
    if (half == 0) {
      *(float4*)(hout + (size_t)node * F + hm * 4) = make_float4(h0, h1, h2, h3);
    }
  } else {
    float acc[C_OUT];
#pragma unroll
    for (int c = 0; c < C_OUT; ++c) {
      float4 w = *(const float4*)(lw + (size_t)c * F + hm * 4);
      float v = h0 * w.x + h1 * w.y + h2 * w.z + h3 * w.w;
      v += __shfl_xor(v, 1); v += __shfl_xor(v, 2);
      v += __shfl_xor(v, 4); v += __shfl_xor(v, 8);
      v += __shfl_xor(v, 16);
      acc[c] = v + lb[c];
    }
    float mx = acc[0];
#pragma unroll
    for (int c = 1; c < C_OUT; ++c) mx = fmaxf(mx, acc[c]);
    float s = 0.f;
#pragma unroll
    for (int c = 0; c < C_OUT; ++c) s += expf(acc[c] - mx);
    float lse = mx + logf(s);
#pragma unroll
    for (int c = 0; c < C_OUT; ++c)
      if (lane == c) outp[(size_t)node * C_OUT + c] = acc[c] - lse;
  }
}

extern "C" void kernel_launch(void* const* d_in, const int* in_sizes, int n_in,
                              void* d_out, int out_size, void* d_ws, size_t ws_size,
                              hipStream_t stream) {
  const float* x    = (const float*)d_in[0];
  const int*   ei   = (const int*)d_in[1];
  const float* W1   = (const float*)d_in[2];
  const float* wih1 = (const float*)d_in[3];
  const float* whh1 = (const float*)d_in[4];
  const float* bih1 = (const float*)d_in[5];
  const float* bhh1 = (const float*)d_in[6];
  const float* W2   = (const float*)d_in[7];
  const float* wih2 = (const float*)d_in[8];
  const float* whh2 = (const float*)d_in[9];
  const float* bih2 = (const float*)d_in[10];
  const float* bhh2 = (const float*)d_in[11];
  const float* lw   = (const float*)d_in[12];
  const float* lb   = (const float*)d_in[13];
  float* out = (float*)d_out;

  int N = in_sizes[0] / F;
  int E = in_sizes[1] / 2;
  const int* src = ei;
  const int* dst = ei + E;
  int nb = (N + SB - 1) / SB;   // 196 for N=50000 (must be <= 256)
  int ng = (N + 15) / 16;       // 16-row groups
  int ngemm = (ng + 3) / 4;     // gemm blocks (4 waves each)
  int nfill = (E + 255) / 256;  // fill blocks

  float* ws   = (float*)d_ws;
  unsigned* bufA = (unsigned*)ws;               // N*32 uints (fp8 rows, 128 B each)
  float* bufB = (float*)(bufA + (size_t)N * 32); // N*F floats (h)
  float* dinv = bufB + (size_t)N * F;           // N
  unsigned short* Bhi1 = (unsigned short*)(dinv + N);  // 16384 each
  unsigned short* Blo1 = Bhi1 + F * F;
  unsigned short* Bhi2 = Blo1 + F * F;
  unsigned short* Blo2 = Bhi2 + F * F;
  int* counts = (int*)(Blo2 + F * F);      // N
  int* rowptr = counts + N;                // N+1
  int* rank   = rowptr + N + 1;            // E
  int* incl   = rank + E;                  // N
  int* blocksum = incl + N;                // nb (<=256)
  int* csr_src = blocksum + 256;           // E

  // evolve weights (both layers, packed bf16 hi/lo fragments) + zero counts
  gru_evolve2_k<<<128 + nb, 256, 0, stream>>>(W1, wih1, whh1, bih1, bhh1,
                                              W2, wih2, whh2, bih2, bhh2,
                                              Bhi1, Blo1, Bhi2, Blo2, counts, N);

  // ----- CSR build + normalization (parallel scan) -----
  count_rank_k<<<(E + 255) / 256, 256, 0, stream>>>(dst, counts, rank, E);
  scan_local_k<<<nb, SB, 0, stream>>>(counts, incl, blocksum, N);
  scan_finish_k<<<nb, SB, 0, stream>>>(counts, incl, blocksum, rowptr, dinv, N, nb);

  // ----- layer 1 gemm + csr fill (independent; fused dispatch) -----
  fill_gemm_k<<<ngemm + nfill, 256, 0, stream>>>(x, Bhi1, Blo1, dinv, bufA, N, ngemm,
                                                 src, dst, rank, rowptr, csr_src, E);
  agg_fp8_k<false><<<(N + 3) / 4, 256, 0, stream>>>(rowptr, csr_src, dinv, bufA, bufB,
                                                    nullptr, nullptr, nullptr, N);

  // ----- layer 2 (logits fused) -----
  gemm_mfma_k<<<ngemm, 256, 0, stream>>>(bufB, Bhi2, Blo2, dinv, bufA, N);
  agg_fp8_k<true><<<(N + 3) / 4, 256, 0, stream>>>(rowptr, csr_src, dinv, bufA, nullptr,
                                                   lw, lb, out, N);
}